// Round 1
// baseline (14164.421 us; speedup 1.0000x reference)
//
#include <hip/hip_runtime.h>
#include <hip/hip_bf16.h>
#include <math.h>

#define NB 2048
#define NF 512
#define NM 16
#define NH 32
#define NWd 32
#define NK 121
#define NHW 1024
#define NMK 1936

static __device__ __forceinline__ float b2f(unsigned short s) {
  return __uint_as_float(((unsigned int)s) << 16);
}
static __device__ __forceinline__ unsigned short f2b(float f) {
  unsigned int u = __float_as_uint(f);
  unsigned int lsb = (u >> 16) & 1u;
  u += 0x7fffu + lsb;
  return (unsigned short)(u >> 16);
}

// ---------------------------------------------------------------------------
// K1: MLP  x=[features|pos_enc] (576) -> 256 -> 128 -> 1936 write_vals
// 8 batch rows per block, 256 threads.
// ---------------------------------------------------------------------------
__global__ __launch_bounds__(256) void k_mlp(
    const float* __restrict__ feat, const float* __restrict__ gaze,
    const float* __restrict__ w1, const float* __restrict__ b1,
    const float* __restrict__ w2, const float* __restrict__ b2,
    const float* __restrict__ wv, const float* __restrict__ bv,
    float* __restrict__ wvout) {
  __shared__ float xs[8][576];
  __shared__ float g1[8][256];
  __shared__ float g2[8][128];
  const int t = threadIdx.x;
  const int b0 = blockIdx.x * 8;

  for (int e = t; e < 8 * 512; e += 256) {
    int r = e >> 9, i = e & 511;
    xs[r][i] = feat[(size_t)(b0 + r) * NF + i];
  }
  // positional encoding: 8 rows x 64 entries
  for (int e = t; e < 8 * 64; e += 256) {
    int r = e >> 6, i = e & 63;
    int axis = i >> 5;        // 0 = x, 1 = y
    int ii = i & 31;
    int jj = ii >> 1;         // frequency index 0..15
    int isc = ii & 1;         // 0 = sin, 1 = cos
    float p = gaze[(size_t)(b0 + r) * 2 + axis];
    // div[jj] = exp(-(2*jj) * ln(10000)/32)
    float dv = expf(-(float)(2 * jj) * 0.28782313662425575f);
    float ang = p * dv;
    xs[r][512 + i] = isc ? cosf(ang) : sinf(ang);
  }
  __syncthreads();
  // layer1: 576 -> 256
  {
    float acc[8];
    float bb = b1[t];
#pragma unroll
    for (int r = 0; r < 8; r++) acc[r] = bb;
    for (int i = 0; i < 576; i++) {
      float w = w1[(size_t)i * 256 + t];
#pragma unroll
      for (int r = 0; r < 8; r++) acc[r] = fmaf(xs[r][i], w, acc[r]);
    }
#pragma unroll
    for (int r = 0; r < 8; r++) g1[r][t] = fmaxf(acc[r], 0.f);
  }
  __syncthreads();
  // layer2: 256 -> 128
  if (t < 128) {
    float acc[8];
    float bb = b2[t];
#pragma unroll
    for (int r = 0; r < 8; r++) acc[r] = bb;
    for (int i = 0; i < 256; i++) {
      float w = w2[(size_t)i * 128 + t];
#pragma unroll
      for (int r = 0; r < 8; r++) acc[r] = fmaf(g1[r][i], w, acc[r]);
    }
#pragma unroll
    for (int r = 0; r < 8; r++) g2[r][t] = fmaxf(acc[r], 0.f);
  }
  __syncthreads();
  // layer3: 128 -> 1936
  for (int j = t; j < NMK; j += 256) {
    float acc[8];
    float bb = bv[j];
#pragma unroll
    for (int r = 0; r < 8; r++) acc[r] = bb;
    for (int i = 0; i < 128; i++) {
      float w = wv[(size_t)i * NMK + j];
#pragma unroll
      for (int r = 0; r < 8; r++) acc[r] = fmaf(g2[r][i], w, acc[r]);
    }
#pragma unroll
    for (int r = 0; r < 8; r++) wvout[(size_t)(b0 + r) * NMK + j] = acc[r];
  }
}

// ---------------------------------------------------------------------------
// K2: geometry + gather + strength gate + windowed scatter + cell update.
// One block per batch, 256 threads. Scatter targets live in an 11x11 window.
// ---------------------------------------------------------------------------
__global__ __launch_bounds__(256) void k_update(
    const float* __restrict__ cell, const float* __restrict__ gaze,
    const float* __restrict__ wvin,
    const float* __restrict__ ws1, const float* __restrict__ bs1,
    const float* __restrict__ ws2, const float* __restrict__ bs2,
    float* __restrict__ updated) {
  __shared__ float numl[16][128];   // [m][local window pos]
  __shared__ float denl[128];
  __shared__ float ws1s[2048];
  __shared__ float bs1s[64];
  __shared__ float ws2s[64];
  __shared__ float nws[121];
  __shared__ float gsum_s;
  __shared__ float bs2s;
  const int t = threadIdx.x;
  const int b = blockIdx.x;

  for (int e = t; e < 16 * 128; e += 256) ((float*)numl)[e] = 0.f;
  if (t < 128) denl[t] = 0.f;
  for (int e = t; e < 2048; e += 256) ws1s[e] = ws1[e];
  if (t < 64) { bs1s[t] = bs1[t]; ws2s[t] = ws2[t]; }
  if (t == 0) bs2s = bs2[0];

  const float gx = fminf(fmaxf(gaze[(size_t)b * 2 + 0] * 31.f, 0.f), 31.f);
  const float gy = fminf(fmaxf(gaze[(size_t)b * 2 + 1] * 31.f, 0.f), 31.f);
  const int x0 = (int)floorf(gx);
  const int y0 = (int)floorf(gy);
  const int wx0 = max(0, x0 - 5);
  const int wy0 = max(0, y0 - 5);

  int xi = 0, yi = 0;
  if (t < NK) {
    int ox = t % 11 - 5;
    int oy = t / 11 - 5;
    xi = min(max(x0 + ox, 0), 31);
    yi = min(max(y0 + oy, 0), 31);
    float dx = (float)xi - gx, dy = (float)yi - gy;
    // 2*sigma^2 = 2*(11/3)^2 = 242/9
    nws[t] = expf(-(dx * dx + dy * dy) * (9.0f / 242.0f));
  }
  __syncthreads();
  if (t == 0) {
    float s = 0.f;
    for (int k = 0; k < NK; k++) s += nws[k];
    gsum_s = fmaxf(s, 1e-8f);
  }
  __syncthreads();

  if (t < NK) {
    const float nw = nws[t] / gsum_s;
    const int idx = yi * 32 + xi;
    const int local = (yi - wy0) * 11 + (xi - wx0);
    float prev[16], wvv[16];
#pragma unroll
    for (int m = 0; m < 16; m++) prev[m] = cell[(size_t)b * 16384 + m * 1024 + idx];
#pragma unroll
    for (int m = 0; m < 16; m++) wvv[m] = wvin[(size_t)b * NMK + t * 16 + m];
    // gate MLP: 32 -> 64 -> 1 sigmoid
    float z2 = bs2s;
    for (int j = 0; j < 64; j++) {
      float z = bs1s[j];
#pragma unroll
      for (int i = 0; i < 16; i++) z = fmaf(prev[i], ws1s[i * 64 + j], z);
#pragma unroll
      for (int i = 0; i < 16; i++) z = fmaf(wvv[i], ws1s[(16 + i) * 64 + j], z);
      z = fmaxf(z, 0.f);
      z2 = fmaf(z, ws2s[j], z2);
    }
    float gstr = 1.f / (1.f + expf(-z2));
    float w = nw * gstr;
    atomicAdd(&denl[local], w);
#pragma unroll
    for (int m = 0; m < 16; m++) {
      float nv = (1.f - w) * prev[m] + w * wvv[m];
      atomicAdd(&numl[m][local], w * nv);
    }
  }
  __syncthreads();

  for (int e = t; e < 16384; e += 256) {
    int m = e >> 10, hw = e & 1023;
    int yy = hw >> 5, xx = hw & 31;
    int wy = yy - wy0, wx = xx - wx0;
    float dv = 0.f, nm = 0.f;
    if ((unsigned)wy < 11u && (unsigned)wx < 11u) {
      int local = wy * 11 + wx;
      dv = denl[local];
      nm = numl[m][local];
    }
    float keep = 1.f - fminf(dv, 1.f);
    updated[(size_t)b * 16384 + e] = keep * cell[(size_t)b * 16384 + e] + nm;
  }
}

// ---------------------------------------------------------------------------
// K3: fused conv1(16->128,3x3,relu) + conv2(128->64,3x3,relu) + adaptive pool 3x3.
// One block per batch, 256 threads, 8 tiles of 4 output rows.
// LDS: u (bf16, 8 rows + x-halo), y1 (bf16, 6 rows), rowbin, pool. 63.2 KB.
// ---------------------------------------------------------------------------
__global__ __launch_bounds__(256) void k_conv(
    const float* __restrict__ updated,
    const float* __restrict__ ck1, const float* __restrict__ cb1,
    const float* __restrict__ ck2, const float* __restrict__ cb2,
    float* __restrict__ ypool) {
  __shared__ unsigned short u[16 * 8 * 34];      // [ci][lr 0..7][x34]
  __shared__ unsigned short y1b[128 * 6 * 32];   // [c1][lry 0..5][x]
  __shared__ float rowbin[64][4][3];
  __shared__ float pool[64][3][3];
  const int t = threadIdx.x;
  const int b = blockIdx.x;
  const float* ub = updated + (size_t)b * 16384;
  const int x = t & 31;
  const int g = t >> 5;          // 0..7

  for (int e = t; e < 64 * 9; e += 256) ((float*)pool)[e] = 0.f;
  for (int e = t; e < 64 * 12; e += 256) ((float*)rowbin)[e] = 0.f;
  __syncthreads();

  for (int ti = 0; ti < 8; ti++) {
    const int r0 = ti * 4;
    // ---- Phase A: stage updated rows r0-2 .. r0+5 (zero-padded) ----
    for (int e = t; e < 16 * 8 * 34; e += 256) {
      int x34 = e % 34;
      int q = e / 34;
      int lr = q & 7;
      int ci = q >> 3;
      int gr = r0 - 2 + lr;
      int gxc = x34 - 1;
      float v = 0.f;
      if (gr >= 0 && gr < 32 && gxc >= 0 && gxc < 32)
        v = ub[ci * 1024 + gr * 32 + gxc];
      u[e] = f2b(v);
    }
    __syncthreads();

    // ---- Phase B: conv1 -> y1 rows r0-1 .. r0+4 (bf16 in LDS) ----
    for (int cb = 0; cb < 4; cb++) {
      float acc[4][6];
#pragma unroll
      for (int i = 0; i < 4; i++) {
        float bb = cb1[g + 8 * i + 32 * cb];
#pragma unroll
        for (int rr = 0; rr < 6; rr++) acc[i][rr] = bb;
      }
      for (int ci = 0; ci < 16; ci++) {
#pragma unroll
        for (int dy = 0; dy < 3; dy++) {
          float w[4][3];
#pragma unroll
          for (int i = 0; i < 4; i++) {
            int c1 = g + 8 * i + 32 * cb;
            int base = ((c1 * 16 + ci) * 3 + dy) * 3;
            w[i][0] = ck1[base + 0];
            w[i][1] = ck1[base + 1];
            w[i][2] = ck1[base + 2];
          }
#pragma unroll
          for (int lry = 0; lry < 6; lry++) {
            const unsigned short* up = &u[(ci * 8 + lry + dy) * 34 + x];
            float u0 = b2f(up[0]), u1 = b2f(up[1]), u2 = b2f(up[2]);
#pragma unroll
            for (int i = 0; i < 4; i++) {
              acc[i][lry] = fmaf(u0, w[i][0], acc[i][lry]);
              acc[i][lry] = fmaf(u1, w[i][1], acc[i][lry]);
              acc[i][lry] = fmaf(u2, w[i][2], acc[i][lry]);
            }
          }
        }
      }
#pragma unroll
      for (int i = 0; i < 4; i++) {
        int c1 = g + 8 * i + 32 * cb;
#pragma unroll
        for (int lry = 0; lry < 6; lry++) {
          int ry = r0 - 1 + lry;
          float v = (ry >= 0 && ry < 32) ? fmaxf(acc[i][lry], 0.f) : 0.f;
          y1b[(c1 * 6 + lry) * 32 + x] = f2b(v);
        }
      }
    }
    __syncthreads();

    // ---- Phase C: conv2 rows r0..r0+3, relu, accumulate rowbin ----
    {
      float acc2[8][4];
#pragma unroll
      for (int i = 0; i < 8; i++) {
        float bb = cb2[g + 8 * i];
#pragma unroll
        for (int rr = 0; rr < 4; rr++) acc2[i][rr] = bb;
      }
      const int xm1 = (x > 0) ? x - 1 : 0;
      const int xp1 = (x < 31) ? x + 1 : 31;
      const bool hasL = (x > 0), hasR = (x < 31);
      for (int c1 = 0; c1 < 128; c1++) {
#pragma unroll
        for (int dy = 0; dy < 3; dy++) {
          float yv[4][3];
#pragma unroll
          for (int rr = 0; rr < 4; rr++) {
            const unsigned short* yp = &y1b[(c1 * 6 + rr + dy) * 32];
            yv[rr][0] = hasL ? b2f(yp[xm1]) : 0.f;
            yv[rr][1] = b2f(yp[x]);
            yv[rr][2] = hasR ? b2f(yp[xp1]) : 0.f;
          }
#pragma unroll
          for (int i = 0; i < 8; i++) {
            int c2 = g + 8 * i;
            int base = ((c2 * 128 + c1) * 3 + dy) * 3;
            float w0 = ck2[base + 0];
            float w1v = ck2[base + 1];
            float w2v = ck2[base + 2];
#pragma unroll
            for (int rr = 0; rr < 4; rr++) {
              acc2[i][rr] = fmaf(yv[rr][0], w0, acc2[i][rr]);
              acc2[i][rr] = fmaf(yv[rr][1], w1v, acc2[i][rr]);
              acc2[i][rr] = fmaf(yv[rr][2], w2v, acc2[i][rr]);
            }
          }
        }
      }
      // relu + column-bin accumulation (x->pw: [0,10],[10,21],[21,31])
#pragma unroll
      for (int i = 0; i < 8; i++) {
        int c2 = g + 8 * i;
#pragma unroll
        for (int rr = 0; rr < 4; rr++) {
          float v = fmaxf(acc2[i][rr], 0.f);
          if (x <= 10) atomicAdd(&rowbin[c2][rr][0], v);
          if (x >= 10 && x <= 21) atomicAdd(&rowbin[c2][rr][1], v);
          if (x >= 21) atomicAdd(&rowbin[c2][rr][2], v);
        }
      }
    }
    __syncthreads();

    // ---- Phase D: fold rowbin into pool (row->ph: [0,10],[10,21],[21,31]) ----
    if (t < 192) {
      int c2 = t / 3, pw = t % 3;
#pragma unroll
      for (int lrr = 0; lrr < 4; lrr++) {
        int rr = r0 + lrr;
        float v = rowbin[c2][lrr][pw];
        rowbin[c2][lrr][pw] = 0.f;
        if (rr <= 10) pool[c2][0][pw] += v;
        if (rr >= 10 && rr <= 21) pool[c2][1][pw] += v;
        if (rr >= 21) pool[c2][2][pw] += v;
      }
    }
    __syncthreads();
  }

  // ---- finalize: divide by region sizes, write pooled vector ----
  for (int e = t; e < 576; e += 256) {
    int c2 = e / 9, ph = (e % 9) / 3, pw = e % 3;
    const int hsz0 = (ph == 1) ? 12 : 11;
    const int wsz0 = (pw == 1) ? 12 : 11;
    ypool[(size_t)b * 576 + e] = pool[c2][ph][pw] / (float)(hsz0 * wsz0);
  }
}

// ---------------------------------------------------------------------------
// K4: out = ypool @ wo + bo   (2048x576)@(576x576); 8 rows per block.
// ---------------------------------------------------------------------------
__global__ __launch_bounds__(256) void k_out(
    const float* __restrict__ ypool, const float* __restrict__ wo,
    const float* __restrict__ bo, float* __restrict__ out) {
  __shared__ float ys[8][576];
  const int t = threadIdx.x;
  const int b0 = blockIdx.x * 8;
  for (int e = t; e < 8 * 576; e += 256) {
    int r = e / 576, i = e % 576;
    ys[r][i] = ypool[(size_t)(b0 + r) * 576 + i];
  }
  __syncthreads();
  for (int j = t; j < 576; j += 256) {
    float acc[8];
    float bb = bo[j];
#pragma unroll
    for (int r = 0; r < 8; r++) acc[r] = bb;
    for (int i = 0; i < 576; i++) {
      float w = wo[(size_t)i * 576 + j];
#pragma unroll
      for (int r = 0; r < 8; r++) acc[r] = fmaf(ys[r][i], w, acc[r]);
    }
#pragma unroll
    for (int r = 0; r < 8; r++) out[(size_t)(b0 + r) * 576 + j] = acc[r];
  }
}

extern "C" void kernel_launch(void* const* d_in, const int* in_sizes, int n_in,
                              void* d_out, int out_size, void* d_ws, size_t ws_size,
                              hipStream_t stream) {
  (void)in_sizes; (void)n_in; (void)out_size; (void)ws_size;
  const float* feat = (const float*)d_in[0];
  const float* cell = (const float*)d_in[1];
  const float* gaze = (const float*)d_in[2];
  const float* w1   = (const float*)d_in[3];
  const float* b1   = (const float*)d_in[4];
  const float* w2   = (const float*)d_in[5];
  const float* b2   = (const float*)d_in[6];
  const float* wv   = (const float*)d_in[7];
  const float* bv   = (const float*)d_in[8];
  const float* ws1  = (const float*)d_in[9];
  const float* bs1  = (const float*)d_in[10];
  const float* ws2  = (const float*)d_in[11];
  const float* bs2  = (const float*)d_in[12];
  const float* ck1  = (const float*)d_in[13];
  const float* cb1  = (const float*)d_in[14];
  const float* ck2  = (const float*)d_in[15];
  const float* cb2  = (const float*)d_in[16];
  const float* wo   = (const float*)d_in[17];
  const float* bo   = (const float*)d_in[18];

  float* out0    = (float*)d_out;                    // (B,576)
  float* updated = out0 + (size_t)NB * 576;          // (B,16,32,32)
  float* wvout   = (float*)d_ws;                     // B*1936
  float* ypool   = wvout + (size_t)NB * NMK;         // B*576

  k_mlp<<<dim3(NB / 8), dim3(256), 0, stream>>>(feat, gaze, w1, b1, w2, b2, wv, bv, wvout);
  k_update<<<dim3(NB), dim3(256), 0, stream>>>(cell, gaze, wvout, ws1, bs1, ws2, bs2, updated);
  k_conv<<<dim3(NB), dim3(256), 0, stream>>>(updated, ck1, cb1, ck2, cb2, ypool);
  k_out<<<dim3(NB / 8), dim3(256), 0, stream>>>(ypool, wo, bo, out0);
}

// Round 2
// 6844.414 us; speedup vs baseline: 2.0695x; 2.0695x over previous
//
#include <hip/hip_runtime.h>
#include <hip/hip_bf16.h>
#include <math.h>

#define NB 2048
#define NF 512
#define NM 16
#define NK 121
#define NMK 1936

typedef __attribute__((ext_vector_type(8))) short bf16x8;
typedef __attribute__((ext_vector_type(4))) float f32x4;

static __device__ __forceinline__ float b2f(unsigned short s) {
  return __uint_as_float(((unsigned int)s) << 16);
}
static __device__ __forceinline__ unsigned short f2b(float f) {
  unsigned int u = __float_as_uint(f);
  unsigned int lsb = (u >> 16) & 1u;
  u += 0x7fffu + lsb;
  return (unsigned short)(u >> 16);
}

// ---------------------------------------------------------------------------
// K0: pre-pack conv weights into MFMA A-fragment order (bf16).
// ap1: conv1 (128 x K160: 9 shifts x 16ci + 16 zero-K)   [kc(5)][mt(8)][lane][8]
// ap2: conv2 (64 x K1152: 9 shifts x 128c1)              [s(9)][kc(4)][mt(4)][lane][8]
// A[m][k]: m = lane&15, k = (lane>>4)*8 + j.
// ---------------------------------------------------------------------------
__global__ __launch_bounds__(256) void k_pack(
    const float* __restrict__ ck1, const float* __restrict__ ck2,
    unsigned short* __restrict__ ap1, unsigned short* __restrict__ ap2) {
  int i = blockIdx.x * 256 + threadIdx.x;
  if (i < 20480) {
    int j = i & 7, lane = (i >> 3) & 63, mt = (i >> 9) & 7, kc = i >> 12;
    int kk = kc * 32 + ((lane >> 4) << 3) + j;
    int s = kk >> 4, ci = kk & 15;
    int c1 = mt * 16 + (lane & 15);
    float v = 0.f;
    if (s < 9) v = ck1[((c1 * 16 + ci) * 3 + s / 3) * 3 + (s % 3)];
    ap1[i] = f2b(v);
  }
  int i2 = i - 20480;
  if (i2 >= 0 && i2 < 73728) {
    int j = i2 & 7, lane = (i2 >> 3) & 63, mt = (i2 >> 9) & 3, kc = (i2 >> 11) & 3, s = i2 >> 13;
    int c2 = mt * 16 + (lane & 15);
    int c1 = kc * 32 + ((lane >> 4) << 3) + j;
    float v = ck2[((c2 * 128 + c1) * 3 + s / 3) * 3 + (s % 3)];
    ap2[i2] = f2b(v);
  }
}

// ---------------------------------------------------------------------------
// K1: MLP  x=[features|pos_enc] (576) -> 256 -> 128 -> 1936 write_vals
// ---------------------------------------------------------------------------
__global__ __launch_bounds__(256) void k_mlp(
    const float* __restrict__ feat, const float* __restrict__ gaze,
    const float* __restrict__ w1, const float* __restrict__ b1,
    const float* __restrict__ w2, const float* __restrict__ b2,
    const float* __restrict__ wv, const float* __restrict__ bv,
    float* __restrict__ wvout) {
  __shared__ float xs[8][576];
  __shared__ float g1[8][256];
  __shared__ float g2[8][128];
  const int t = threadIdx.x;
  const int b0 = blockIdx.x * 8;

  for (int e = t; e < 8 * 512; e += 256) {
    int r = e >> 9, i = e & 511;
    xs[r][i] = feat[(size_t)(b0 + r) * NF + i];
  }
  for (int e = t; e < 8 * 64; e += 256) {
    int r = e >> 6, i = e & 63;
    int axis = i >> 5;
    int ii = i & 31;
    int jj = ii >> 1;
    int isc = ii & 1;
    float p = gaze[(size_t)(b0 + r) * 2 + axis];
    float dv = expf(-(float)(2 * jj) * 0.28782313662425575f);
    float ang = p * dv;
    xs[r][512 + i] = isc ? cosf(ang) : sinf(ang);
  }
  __syncthreads();
  {
    float acc[8];
    float bb = b1[t];
#pragma unroll
    for (int r = 0; r < 8; r++) acc[r] = bb;
    for (int i = 0; i < 576; i++) {
      float w = w1[(size_t)i * 256 + t];
#pragma unroll
      for (int r = 0; r < 8; r++) acc[r] = fmaf(xs[r][i], w, acc[r]);
    }
#pragma unroll
    for (int r = 0; r < 8; r++) g1[r][t] = fmaxf(acc[r], 0.f);
  }
  __syncthreads();
  if (t < 128) {
    float acc[8];
    float bb = b2[t];
#pragma unroll
    for (int r = 0; r < 8; r++) acc[r] = bb;
    for (int i = 0; i < 256; i++) {
      float w = w2[(size_t)i * 128 + t];
#pragma unroll
      for (int r = 0; r < 8; r++) acc[r] = fmaf(g1[r][i], w, acc[r]);
    }
#pragma unroll
    for (int r = 0; r < 8; r++) g2[r][t] = fmaxf(acc[r], 0.f);
  }
  __syncthreads();
  for (int j = t; j < NMK; j += 256) {
    float acc[8];
    float bb = bv[j];
#pragma unroll
    for (int r = 0; r < 8; r++) acc[r] = bb;
    for (int i = 0; i < 128; i++) {
      float w = wv[(size_t)i * NMK + j];
#pragma unroll
      for (int r = 0; r < 8; r++) acc[r] = fmaf(g2[r][i], w, acc[r]);
    }
#pragma unroll
    for (int r = 0; r < 8; r++) wvout[(size_t)(b0 + r) * NMK + j] = acc[r];
  }
}

// ---------------------------------------------------------------------------
// K2: gather + strength gate + windowed scatter + cell update.
// ---------------------------------------------------------------------------
__global__ __launch_bounds__(256) void k_update(
    const float* __restrict__ cell, const float* __restrict__ gaze,
    const float* __restrict__ wvin,
    const float* __restrict__ ws1, const float* __restrict__ bs1,
    const float* __restrict__ ws2, const float* __restrict__ bs2,
    float* __restrict__ updated) {
  __shared__ float numl[16][128];
  __shared__ float denl[128];
  __shared__ float ws1s[2048];
  __shared__ float bs1s[64];
  __shared__ float ws2s[64];
  __shared__ float nws[121];
  __shared__ float gsum_s;
  __shared__ float bs2s;
  const int t = threadIdx.x;
  const int b = blockIdx.x;

  for (int e = t; e < 16 * 128; e += 256) ((float*)numl)[e] = 0.f;
  if (t < 128) denl[t] = 0.f;
  for (int e = t; e < 2048; e += 256) ws1s[e] = ws1[e];
  if (t < 64) { bs1s[t] = bs1[t]; ws2s[t] = ws2[t]; }
  if (t == 0) bs2s = bs2[0];

  const float gx = fminf(fmaxf(gaze[(size_t)b * 2 + 0] * 31.f, 0.f), 31.f);
  const float gy = fminf(fmaxf(gaze[(size_t)b * 2 + 1] * 31.f, 0.f), 31.f);
  const int x0 = (int)floorf(gx);
  const int y0 = (int)floorf(gy);
  const int wx0 = max(0, x0 - 5);
  const int wy0 = max(0, y0 - 5);

  int xi = 0, yi = 0;
  if (t < NK) {
    int ox = t % 11 - 5;
    int oy = t / 11 - 5;
    xi = min(max(x0 + ox, 0), 31);
    yi = min(max(y0 + oy, 0), 31);
    float dx = (float)xi - gx, dy = (float)yi - gy;
    nws[t] = expf(-(dx * dx + dy * dy) * (9.0f / 242.0f));
  }
  __syncthreads();
  if (t == 0) {
    float s = 0.f;
    for (int k = 0; k < NK; k++) s += nws[k];
    gsum_s = fmaxf(s, 1e-8f);
  }
  __syncthreads();

  if (t < NK) {
    const float nw = nws[t] / gsum_s;
    const int idx = yi * 32 + xi;
    const int local = (yi - wy0) * 11 + (xi - wx0);
    float prev[16], wvv[16];
#pragma unroll
    for (int m = 0; m < 16; m++) prev[m] = cell[(size_t)b * 16384 + m * 1024 + idx];
#pragma unroll
    for (int m = 0; m < 16; m++) wvv[m] = wvin[(size_t)b * NMK + t * 16 + m];
    float z2 = bs2s;
    for (int j = 0; j < 64; j++) {
      float z = bs1s[j];
#pragma unroll
      for (int i = 0; i < 16; i++) z = fmaf(prev[i], ws1s[i * 64 + j], z);
#pragma unroll
      for (int i = 0; i < 16; i++) z = fmaf(wvv[i], ws1s[(16 + i) * 64 + j], z);
      z = fmaxf(z, 0.f);
      z2 = fmaf(z, ws2s[j], z2);
    }
    float gstr = 1.f / (1.f + expf(-z2));
    float w = nw * gstr;
    atomicAdd(&denl[local], w);
#pragma unroll
    for (int m = 0; m < 16; m++) {
      float nv = (1.f - w) * prev[m] + w * wvv[m];
      atomicAdd(&numl[m][local], w * nv);
    }
  }
  __syncthreads();

  for (int e = t; e < 16384; e += 256) {
    int m = e >> 10, hw = e & 1023;
    int yy = hw >> 5, xx = hw & 31;
    int wy = yy - wy0, wx = xx - wx0;
    float dv = 0.f, nm = 0.f;
    if ((unsigned)wy < 11u && (unsigned)wx < 11u) {
      int local = wy * 11 + wx;
      dv = denl[local];
      nm = numl[m][local];
    }
    float keep = 1.f - fminf(dv, 1.f);
    updated[(size_t)b * 16384 + e] = keep * cell[(size_t)b * 16384 + e] + nm;
  }
}

// ---------------------------------------------------------------------------
// K3: MFMA implicit-GEMM conv1(16->128) + conv2(128->64) + adaptive pool 3x3.
// One block per batch, 4 waves. Strips of 4 output rows, 8 strips.
// LDS: u[8][34][16] bf16 (8.5K), y1[6][32][136] bf16 (51K, pad->16B-aligned,
// 4-bank lane stride = conflict-minimal), pool (2.3K). Total 63,232 B -> 2 blk/CU.
// ---------------------------------------------------------------------------
__global__ __launch_bounds__(256, 2) void k_conv2m(
    const float* __restrict__ updated,
    const unsigned short* __restrict__ ap1, const float* __restrict__ cb1,
    const unsigned short* __restrict__ ap2, const float* __restrict__ cb2,
    float* __restrict__ ypool) {
  __shared__ unsigned short u[8][34][16];
  __shared__ unsigned short y1[6][32][136];
  __shared__ float pool[64][3][3];
  const int t = threadIdx.x;
  const int b = blockIdx.x;
  const float* ub = updated + (size_t)b * 16384;
  const int lane = t & 63;
  const int w = t >> 6;       // wave 0..3
  const int ln = lane & 15;
  const int q = lane >> 4;

  for (int e = t; e < 576; e += 256) ((float*)pool)[e] = 0.f;

  for (int ti = 0; ti < 8; ti++) {
    const int r0 = ti * 4;
    // ---- Phase A: stage u rows r0-2..r0+5 (global fp32 NCHW -> LDS bf16 NHWC) ----
    for (int e = t; e < 4352; e += 256) {
      int col = e % 34;
      int tmp = e / 34;
      int lr = tmp & 7;
      int ci = tmp >> 3;
      int gr = r0 - 2 + lr, gxc = col - 1;
      float v = 0.f;
      if ((unsigned)gr < 32u && (unsigned)gxc < 32u) v = ub[ci * 1024 + gr * 32 + gxc];
      u[lr][col][ci] = f2b(v);
    }
    __syncthreads();

    // ---- Phase B: conv1 via MFMA. y1 strip rows 0..5 (global r0-1..r0+4) ----
    for (int i = 0; i < 3; i++) {
      const int nt = w + 4 * i;          // 12 n-tiles over 4 waves
      const int ry = nt >> 1;            // y1 strip row
      const int gy1 = r0 - 1 + ry;       // global y1 row
      const int x = ((nt & 1) << 4) + ln;
      f32x4 acc[8];
#pragma unroll
      for (int mt = 0; mt < 8; mt++) {
        int c1b = mt * 16 + q * 4;
        acc[mt] = f32x4{cb1[c1b], cb1[c1b + 1], cb1[c1b + 2], cb1[c1b + 3]};
      }
#pragma unroll
      for (int kc = 0; kc < 5; kc++) {
        int kk0 = kc * 32 + q * 8;
        int s = kk0 >> 4;               // shift id (lane-dependent via q)
        bf16x8 bfrag;
        if (s < 9) {
          int dy = s / 3, dx = s % 3;
          bfrag = *(const bf16x8*)&u[ry + dy][x + dx][kk0 & 15];
        } else {
          bfrag = bf16x8{0, 0, 0, 0, 0, 0, 0, 0};
        }
#pragma unroll
        for (int mt = 0; mt < 8; mt++) {
          bf16x8 afrag = *(const bf16x8*)(ap1 + (((kc * 8 + mt) * 64 + lane) << 3));
          acc[mt] = __builtin_amdgcn_mfma_f32_16x16x32_bf16(afrag, bfrag, acc[mt], 0, 0, 0);
        }
      }
      const bool inr = ((unsigned)gy1 < 32u);
#pragma unroll
      for (int mt = 0; mt < 8; mt++) {
        float v0 = inr ? fmaxf(acc[mt][0], 0.f) : 0.f;
        float v1 = inr ? fmaxf(acc[mt][1], 0.f) : 0.f;
        float v2 = inr ? fmaxf(acc[mt][2], 0.f) : 0.f;
        float v3 = inr ? fmaxf(acc[mt][3], 0.f) : 0.f;
        uint2 pk;
        pk.x = (unsigned)f2b(v0) | ((unsigned)f2b(v1) << 16);
        pk.y = (unsigned)f2b(v2) | ((unsigned)f2b(v3) << 16);
        *(uint2*)&y1[ry][x][mt * 16 + q * 4] = pk;
      }
    }
    __syncthreads();

    // ---- Phase C: conv2 via MFMA + pool accumulate. Wave w -> y2 row r0+w ----
    {
      const int grow = r0 + w;
      const bool p0 = grow <= 10, p1 = (grow >= 10 && grow <= 21), p2 = grow >= 21;
#pragma unroll
      for (int h = 0; h < 2; h++) {
        const int xg = (h << 4) + ln;
        f32x4 acc[4];
#pragma unroll
        for (int mt = 0; mt < 4; mt++) {
          int c2b = mt * 16 + q * 4;
          acc[mt] = f32x4{cb2[c2b], cb2[c2b + 1], cb2[c2b + 2], cb2[c2b + 3]};
        }
#pragma unroll
        for (int s = 0; s < 9; s++) {
          const int dy = s / 3, dx = s % 3;
          const int row = w + dy;
          int c = xg + dx - 1;
          const bool zb = (c < 0) | (c > 31);
          c = min(31, max(0, c));
#pragma unroll
          for (int kc = 0; kc < 4; kc++) {
            bf16x8 bfrag = *(const bf16x8*)&y1[row][c][kc * 32 + q * 8];
            if (zb) bfrag = bf16x8{0, 0, 0, 0, 0, 0, 0, 0};
#pragma unroll
            for (int mt = 0; mt < 4; mt++) {
              bf16x8 afrag =
                  *(const bf16x8*)(ap2 + ((((s * 4 + kc) * 4 + mt) * 64 + lane) << 3));
              acc[mt] = __builtin_amdgcn_mfma_f32_16x16x32_bf16(afrag, bfrag, acc[mt], 0, 0, 0);
            }
          }
        }
        const bool q0 = xg <= 10, q1 = (xg >= 10 && xg <= 21), q2 = xg >= 21;
#pragma unroll
        for (int mt = 0; mt < 4; mt++) {
#pragma unroll
          for (int r = 0; r < 4; r++) {
            int c2 = mt * 16 + q * 4 + r;
            float v = fmaxf(acc[mt][r], 0.f);
            if (p0) {
              if (q0) atomicAdd(&pool[c2][0][0], v);
              if (q1) atomicAdd(&pool[c2][0][1], v);
              if (q2) atomicAdd(&pool[c2][0][2], v);
            }
            if (p1) {
              if (q0) atomicAdd(&pool[c2][1][0], v);
              if (q1) atomicAdd(&pool[c2][1][1], v);
              if (q2) atomicAdd(&pool[c2][1][2], v);
            }
            if (p2) {
              if (q0) atomicAdd(&pool[c2][2][0], v);
              if (q1) atomicAdd(&pool[c2][2][1], v);
              if (q2) atomicAdd(&pool[c2][2][2], v);
            }
          }
        }
      }
    }
    __syncthreads();
  }

  for (int e = t; e < 576; e += 256) {
    int c2 = e / 9, ph = (e % 9) / 3, pw = e % 3;
    const int hsz = (ph == 1) ? 12 : 11;
    const int wsz = (pw == 1) ? 12 : 11;
    ypool[(size_t)b * 576 + e] = pool[c2][ph][pw] / (float)(hsz * wsz);
  }
}

// ---------------------------------------------------------------------------
// K4: out = ypool @ wo + bo
// ---------------------------------------------------------------------------
__global__ __launch_bounds__(256) void k_out(
    const float* __restrict__ ypool, const float* __restrict__ wo,
    const float* __restrict__ bo, float* __restrict__ out) {
  __shared__ float ys[8][576];
  const int t = threadIdx.x;
  const int b0 = blockIdx.x * 8;
  for (int e = t; e < 8 * 576; e += 256) {
    int r = e / 576, i = e % 576;
    ys[r][i] = ypool[(size_t)(b0 + r) * 576 + i];
  }
  __syncthreads();
  for (int j = t; j < 576; j += 256) {
    float acc[8];
    float bb = bo[j];
#pragma unroll
    for (int r = 0; r < 8; r++) acc[r] = bb;
    for (int i = 0; i < 576; i++) {
      float w = wo[(size_t)i * 576 + j];
#pragma unroll
      for (int r = 0; r < 8; r++) acc[r] = fmaf(ys[r][i], w, acc[r]);
    }
#pragma unroll
    for (int r = 0; r < 8; r++) out[(size_t)(b0 + r) * 576 + j] = acc[r];
  }
}

extern "C" void kernel_launch(void* const* d_in, const int* in_sizes, int n_in,
                              void* d_out, int out_size, void* d_ws, size_t ws_size,
                              hipStream_t stream) {
  (void)in_sizes; (void)n_in; (void)out_size; (void)ws_size;
  const float* feat = (const float*)d_in[0];
  const float* cell = (const float*)d_in[1];
  const float* gaze = (const float*)d_in[2];
  const float* w1   = (const float*)d_in[3];
  const float* b1   = (const float*)d_in[4];
  const float* w2   = (const float*)d_in[5];
  const float* b2   = (const float*)d_in[6];
  const float* wv   = (const float*)d_in[7];
  const float* bv   = (const float*)d_in[8];
  const float* ws1  = (const float*)d_in[9];
  const float* bs1  = (const float*)d_in[10];
  const float* ws2  = (const float*)d_in[11];
  const float* bs2  = (const float*)d_in[12];
  const float* ck1  = (const float*)d_in[13];
  const float* cb1  = (const float*)d_in[14];
  const float* ck2  = (const float*)d_in[15];
  const float* cb2  = (const float*)d_in[16];
  const float* wo   = (const float*)d_in[17];
  const float* bo   = (const float*)d_in[18];

  float* out0    = (float*)d_out;                    // (B,576)
  float* updated = out0 + (size_t)NB * 576;          // (B,16,32,32)
  float* wvout   = (float*)d_ws;                     // B*1936 f32
  float* ypool   = wvout + (size_t)NB * NMK;         // B*576 f32
  unsigned short* ap1 = (unsigned short*)(ypool + (size_t)NB * 576);  // 20480 bf16
  unsigned short* ap2 = ap1 + 20480;                                  // 73728 bf16

  k_pack<<<dim3(368), dim3(256), 0, stream>>>(ck1, ck2, ap1, ap2);
  k_mlp<<<dim3(NB / 8), dim3(256), 0, stream>>>(feat, gaze, w1, b1, w2, b2, wv, bv, wvout);
  k_update<<<dim3(NB), dim3(256), 0, stream>>>(cell, gaze, wvout, ws1, bs1, ws2, bs2, updated);
  k_conv2m<<<dim3(NB), dim3(256), 0, stream>>>(updated, ap1, cb1, ap2, cb2, ypool);
  k_out<<<dim3(NB / 8), dim3(256), 0, stream>>>(ypool, wo, bo, out0);
}

// Round 3
// 1563.300 us; speedup vs baseline: 9.0606x; 4.3782x over previous
//
#include <hip/hip_runtime.h>
#include <hip/hip_bf16.h>
#include <math.h>

#define NB 2048
#define NF 512
#define NM 16
#define NK 121
#define NMK 1936

typedef __attribute__((ext_vector_type(8))) short bf16x8;
typedef __attribute__((ext_vector_type(4))) float f32x4;

static __device__ __forceinline__ float b2f(unsigned short s) {
  return __uint_as_float(((unsigned int)s) << 16);
}
static __device__ __forceinline__ unsigned short f2b(float f) {
  unsigned int u = __float_as_uint(f);
  unsigned int lsb = (u >> 16) & 1u;
  u += 0x7fffu + lsb;
  return (unsigned short)(u >> 16);
}

// ---------------------------------------------------------------------------
// K0: pre-pack conv weights into per-wave MFMA A-fragment slices (bf16).
// ap1: [w(4)][kc(5)][m2(2)][lane(64)][j(8)]  -- wave w owns c1 in [32w,32w+32)
// ap2: [mt(4)][s(9)][kc(4)][lane(64)][j(8)]  -- wave mt owns c2 in [16mt,16mt+16)
// A[m][k]: m = lane&15, k = (lane>>4)*8 + j  (16x16x32 A-operand layout).
// ---------------------------------------------------------------------------
__global__ __launch_bounds__(256) void k_pack(
    const float* __restrict__ ck1, const float* __restrict__ ck2,
    unsigned short* __restrict__ ap1, unsigned short* __restrict__ ap2) {
  int i = blockIdx.x * 256 + threadIdx.x;
  if (i < 20480) {
    int j = i & 7, lane = (i >> 3) & 63;
    int m2 = (i >> 9) & 1, kc = (i >> 10) % 5, w = i / 5120;
    int c1 = w * 32 + m2 * 16 + (lane & 15);
    int k = kc * 32 + ((lane >> 4) << 3) + j;
    int s = k >> 4, ci = k & 15;
    float v = 0.f;
    if (s < 9) v = ck1[((c1 * 16 + ci) * 3 + s / 3) * 3 + (s % 3)];
    ap1[i] = f2b(v);
  }
  int i2 = i - 20480;
  if (i2 >= 0 && i2 < 73728) {
    int j = i2 & 7, lane = (i2 >> 3) & 63;
    int kc = (i2 >> 9) & 3, s = (i2 >> 11) % 9, mt = i2 / 18432;
    int c2 = mt * 16 + (lane & 15);
    int c1 = kc * 32 + ((lane >> 4) << 3) + j;
    float v = ck2[((c2 * 128 + c1) * 3 + s / 3) * 3 + (s % 3)];
    ap2[i2] = f2b(v);
  }
}

// ---------------------------------------------------------------------------
// K1: MLP  x=[features|pos_enc] (576) -> 256 -> 128 -> 1936 write_vals
// ---------------------------------------------------------------------------
__global__ __launch_bounds__(256) void k_mlp(
    const float* __restrict__ feat, const float* __restrict__ gaze,
    const float* __restrict__ w1, const float* __restrict__ b1,
    const float* __restrict__ w2, const float* __restrict__ b2,
    const float* __restrict__ wv, const float* __restrict__ bv,
    float* __restrict__ wvout) {
  __shared__ float xs[8][576];
  __shared__ float g1[8][256];
  __shared__ float g2[8][128];
  const int t = threadIdx.x;
  const int b0 = blockIdx.x * 8;

  for (int e = t; e < 8 * 512; e += 256) {
    int r = e >> 9, i = e & 511;
    xs[r][i] = feat[(size_t)(b0 + r) * NF + i];
  }
  for (int e = t; e < 8 * 64; e += 256) {
    int r = e >> 6, i = e & 63;
    int axis = i >> 5;
    int ii = i & 31;
    int jj = ii >> 1;
    int isc = ii & 1;
    float p = gaze[(size_t)(b0 + r) * 2 + axis];
    float dv = expf(-(float)(2 * jj) * 0.28782313662425575f);
    float ang = p * dv;
    xs[r][512 + i] = isc ? cosf(ang) : sinf(ang);
  }
  __syncthreads();
  {
    float acc[8];
    float bb = b1[t];
#pragma unroll
    for (int r = 0; r < 8; r++) acc[r] = bb;
    for (int i = 0; i < 576; i++) {
      float w = w1[(size_t)i * 256 + t];
#pragma unroll
      for (int r = 0; r < 8; r++) acc[r] = fmaf(xs[r][i], w, acc[r]);
    }
#pragma unroll
    for (int r = 0; r < 8; r++) g1[r][t] = fmaxf(acc[r], 0.f);
  }
  __syncthreads();
  if (t < 128) {
    float acc[8];
    float bb = b2[t];
#pragma unroll
    for (int r = 0; r < 8; r++) acc[r] = bb;
    for (int i = 0; i < 256; i++) {
      float w = w2[(size_t)i * 128 + t];
#pragma unroll
      for (int r = 0; r < 8; r++) acc[r] = fmaf(g1[r][i], w, acc[r]);
    }
#pragma unroll
    for (int r = 0; r < 8; r++) g2[r][t] = fmaxf(acc[r], 0.f);
  }
  __syncthreads();
  for (int j = t; j < NMK; j += 256) {
    float acc[8];
    float bb = bv[j];
#pragma unroll
    for (int r = 0; r < 8; r++) acc[r] = bb;
    for (int i = 0; i < 128; i++) {
      float w = wv[(size_t)i * NMK + j];
#pragma unroll
      for (int r = 0; r < 8; r++) acc[r] = fmaf(g2[r][i], w, acc[r]);
    }
#pragma unroll
    for (int r = 0; r < 8; r++) wvout[(size_t)(b0 + r) * NMK + j] = acc[r];
  }
}

// ---------------------------------------------------------------------------
// K2: gather + strength gate + windowed scatter + cell update.
// ---------------------------------------------------------------------------
__global__ __launch_bounds__(256) void k_update(
    const float* __restrict__ cell, const float* __restrict__ gaze,
    const float* __restrict__ wvin,
    const float* __restrict__ ws1, const float* __restrict__ bs1,
    const float* __restrict__ ws2, const float* __restrict__ bs2,
    float* __restrict__ updated) {
  __shared__ float numl[16][128];
  __shared__ float denl[128];
  __shared__ float ws1s[2048];
  __shared__ float bs1s[64];
  __shared__ float ws2s[64];
  __shared__ float nws[121];
  __shared__ float gsum_s;
  __shared__ float bs2s;
  const int t = threadIdx.x;
  const int b = blockIdx.x;

  for (int e = t; e < 16 * 128; e += 256) ((float*)numl)[e] = 0.f;
  if (t < 128) denl[t] = 0.f;
  for (int e = t; e < 2048; e += 256) ws1s[e] = ws1[e];
  if (t < 64) { bs1s[t] = bs1[t]; ws2s[t] = ws2[t]; }
  if (t == 0) bs2s = bs2[0];

  const float gx = fminf(fmaxf(gaze[(size_t)b * 2 + 0] * 31.f, 0.f), 31.f);
  const float gy = fminf(fmaxf(gaze[(size_t)b * 2 + 1] * 31.f, 0.f), 31.f);
  const int x0 = (int)floorf(gx);
  const int y0 = (int)floorf(gy);
  const int wx0 = max(0, x0 - 5);
  const int wy0 = max(0, y0 - 5);

  int xi = 0, yi = 0;
  if (t < NK) {
    int ox = t % 11 - 5;
    int oy = t / 11 - 5;
    xi = min(max(x0 + ox, 0), 31);
    yi = min(max(y0 + oy, 0), 31);
    float dx = (float)xi - gx, dy = (float)yi - gy;
    nws[t] = expf(-(dx * dx + dy * dy) * (9.0f / 242.0f));
  }
  __syncthreads();
  if (t == 0) {
    float s = 0.f;
    for (int k = 0; k < NK; k++) s += nws[k];
    gsum_s = fmaxf(s, 1e-8f);
  }
  __syncthreads();

  if (t < NK) {
    const float nw = nws[t] / gsum_s;
    const int idx = yi * 32 + xi;
    const int local = (yi - wy0) * 11 + (xi - wx0);
    float prev[16], wvv[16];
#pragma unroll
    for (int m = 0; m < 16; m++) prev[m] = cell[(size_t)b * 16384 + m * 1024 + idx];
#pragma unroll
    for (int m = 0; m < 16; m++) wvv[m] = wvin[(size_t)b * NMK + t * 16 + m];
    float z2 = bs2s;
    for (int j = 0; j < 64; j++) {
      float z = bs1s[j];
#pragma unroll
      for (int i = 0; i < 16; i++) z = fmaf(prev[i], ws1s[i * 64 + j], z);
#pragma unroll
      for (int i = 0; i < 16; i++) z = fmaf(wvv[i], ws1s[(16 + i) * 64 + j], z);
      z = fmaxf(z, 0.f);
      z2 = fmaf(z, ws2s[j], z2);
    }
    float gstr = 1.f / (1.f + expf(-z2));
    float w = nw * gstr;
    atomicAdd(&denl[local], w);
#pragma unroll
    for (int m = 0; m < 16; m++) {
      float nv = (1.f - w) * prev[m] + w * wvv[m];
      atomicAdd(&numl[m][local], w * nv);
    }
  }
  __syncthreads();

  for (int e = t; e < 16384; e += 256) {
    int m = e >> 10, hw = e & 1023;
    int yy = hw >> 5, xx = hw & 31;
    int wy = yy - wy0, wx = xx - wx0;
    float dv = 0.f, nm = 0.f;
    if ((unsigned)wy < 11u && (unsigned)wx < 11u) {
      int local = wy * 11 + wx;
      dv = denl[local];
      nm = numl[m][local];
    }
    float keep = 1.f - fminf(dv, 1.f);
    updated[(size_t)b * 16384 + e] = keep * cell[(size_t)b * 16384 + e] + nm;
  }
}

// ---------------------------------------------------------------------------
// K3: MFMA conv1+conv2+pool with ALL weights pinned in VGPRs.
// Wave w owns c1 in [32w,32w+32) (conv1) and c2 in [16w,16w+16) (conv2).
// a2[9][4] = 144 VGPRs, a1[5][2] = 40 VGPRs, loaded once per block.
// LDS: u[8][34][16] bf16, y1[6][32][136] bf16 (2-way banks = free), pool.
// Pool uses shfl_xor 16-lane butterflies -> 4-lane atomics (no contention).
// ---------------------------------------------------------------------------
__global__ __launch_bounds__(256, 2) void k_conv3(
    const float* __restrict__ updated,
    const unsigned short* __restrict__ ap1, const float* __restrict__ cb1,
    const unsigned short* __restrict__ ap2, const float* __restrict__ cb2,
    float* __restrict__ ypool) {
  __shared__ unsigned short u[8][34][16];
  __shared__ unsigned short y1[6][32][136];
  __shared__ float pool[64][3][3];
  const int t = threadIdx.x;
  const int b = blockIdx.x;
  const float* ub = updated + (size_t)b * 16384;
  const int lane = t & 63;
  const int w = t >> 6;        // wave 0..3
  const int ln = lane & 15;
  const int q = lane >> 4;

  const bf16x8 kZ = {0, 0, 0, 0, 0, 0, 0, 0};

  // ---- pin weights in VGPRs (one bulk load per block) ----
  bf16x8 a1[5][2];
#pragma unroll
  for (int kc = 0; kc < 5; kc++)
#pragma unroll
    for (int m2 = 0; m2 < 2; m2++)
      a1[kc][m2] = *(const bf16x8*)(ap1 + (size_t)(((w * 5 + kc) * 2 + m2) * 64 + lane) * 8);
  bf16x8 a2[9][4];
#pragma unroll
  for (int s = 0; s < 9; s++)
#pragma unroll
    for (int kc = 0; kc < 4; kc++)
      a2[s][kc] = *(const bf16x8*)(ap2 + (size_t)((w * 36 + s * 4 + kc) * 64 + lane) * 8);

  f32x4 cb1r[2], cb2r;
#pragma unroll
  for (int m2 = 0; m2 < 2; m2++) {
    int c1b = w * 32 + m2 * 16 + q * 4;
    cb1r[m2] = f32x4{cb1[c1b], cb1[c1b + 1], cb1[c1b + 2], cb1[c1b + 3]};
  }
  {
    int c2b = w * 16 + q * 4;
    cb2r = f32x4{cb2[c2b], cb2[c2b + 1], cb2[c2b + 2], cb2[c2b + 3]};
  }

  for (int e = t; e < 576; e += 256) ((float*)pool)[e] = 0.f;
  __syncthreads();

  for (int ti = 0; ti < 8; ti++) {
    const int r0 = ti * 4;
    // ---- Phase A: stage updated rows r0-2..r0+5 -> u (bf16, NHWC) ----
    for (int e = t; e < 4352; e += 256) {
      int col = e % 34;
      int tmp = e / 34;
      int lr = tmp & 7;
      int ci = tmp >> 3;
      int gr = r0 - 2 + lr, gxc = col - 1;
      float v = 0.f;
      if ((unsigned)gr < 32u && (unsigned)gxc < 32u) v = ub[ci * 1024 + gr * 32 + gxc];
      u[lr][col][ci] = f2b(v);
    }
    __syncthreads();

    // ---- Phase B: conv1. Each wave: its 32 c1, all 12 n-tiles ----
#pragma unroll 1
    for (int nt = 0; nt < 12; nt++) {
      const int ry = nt >> 1, h = nt & 1;
      const int gy1 = r0 - 1 + ry;
      const int x = h * 16 + ln;
      f32x4 acc0 = cb1r[0], acc1 = cb1r[1];
#pragma unroll
      for (int kc = 0; kc < 5; kc++) {
        const int s = 2 * kc + (q >> 1);
        bf16x8 bfrag = kZ;
        if (s < 9) {
          const int dy = s / 3, dx = s % 3;
          bfrag = *(const bf16x8*)&u[ry + dy][x + dx][(q & 1) * 8];
        }
        acc0 = __builtin_amdgcn_mfma_f32_16x16x32_bf16(a1[kc][0], bfrag, acc0, 0, 0, 0);
        acc1 = __builtin_amdgcn_mfma_f32_16x16x32_bf16(a1[kc][1], bfrag, acc1, 0, 0, 0);
      }
      const bool inr = ((unsigned)gy1 < 32u);
#pragma unroll
      for (int m2 = 0; m2 < 2; m2++) {
        f32x4 a = m2 ? acc1 : acc0;
        float v0 = inr ? fmaxf(a[0], 0.f) : 0.f;
        float v1 = inr ? fmaxf(a[1], 0.f) : 0.f;
        float v2 = inr ? fmaxf(a[2], 0.f) : 0.f;
        float v3 = inr ? fmaxf(a[3], 0.f) : 0.f;
        uint2 pk;
        pk.x = (unsigned)f2b(v0) | ((unsigned)f2b(v1) << 16);
        pk.y = (unsigned)f2b(v2) | ((unsigned)f2b(v3) << 16);
        *(uint2*)&y1[ry][x][w * 32 + m2 * 16 + q * 4] = pk;
      }
    }
    __syncthreads();

    // ---- Phase C: conv2. Each wave: its 16 c2, all 8 n-tiles + pool ----
#pragma unroll 1
    for (int nt = 0; nt < 8; nt++) {
      const int rr = nt >> 1, h = nt & 1;
      const int xg = h * 16 + ln;
      f32x4 acc = cb2r;
#pragma unroll
      for (int s = 0; s < 9; s++) {
        const int dy = s / 3, dx = s % 3;
        int c = xg + dx - 1;
        const bool zb = (c < 0) | (c > 31);
        c = min(31, max(0, c));
        const unsigned short* yp = &y1[rr + dy][c][q * 8];
#pragma unroll
        for (int kc = 0; kc < 4; kc++) {
          bf16x8 bfrag = *(const bf16x8*)(yp + kc * 32);
          if (zb) bfrag = kZ;
          acc = __builtin_amdgcn_mfma_f32_16x16x32_bf16(a2[s][kc], bfrag, acc, 0, 0, 0);
        }
      }
      const int grow = r0 + rr;
      const bool p0 = grow <= 10, p1 = (grow >= 10 && grow <= 21), p2 = grow >= 21;
      const float m0 = (xg <= 10) ? 1.f : 0.f;
      const float m1 = (xg >= 10 && xg <= 21) ? 1.f : 0.f;
      const float m2f = (xg >= 21) ? 1.f : 0.f;
#pragma unroll
      for (int r = 0; r < 4; r++) {
        float v = fmaxf(acc[r], 0.f);
        float s0 = v * m0, s1 = v * m1, s2 = v * m2f;
#pragma unroll
        for (int mk = 1; mk < 16; mk <<= 1) {
          s0 += __shfl_xor(s0, mk, 64);
          s1 += __shfl_xor(s1, mk, 64);
          s2 += __shfl_xor(s2, mk, 64);
        }
        if (ln == 0) {
          int c2 = w * 16 + q * 4 + r;
          if (p0) {
            atomicAdd(&pool[c2][0][0], s0);
            atomicAdd(&pool[c2][0][1], s1);
            atomicAdd(&pool[c2][0][2], s2);
          }
          if (p1) {
            atomicAdd(&pool[c2][1][0], s0);
            atomicAdd(&pool[c2][1][1], s1);
            atomicAdd(&pool[c2][1][2], s2);
          }
          if (p2) {
            atomicAdd(&pool[c2][2][0], s0);
            atomicAdd(&pool[c2][2][1], s1);
            atomicAdd(&pool[c2][2][2], s2);
          }
        }
      }
    }
    __syncthreads();
  }

  for (int e = t; e < 576; e += 256) {
    int c2 = e / 9, ph = (e % 9) / 3, pw = e % 3;
    const int hsz = (ph == 1) ? 12 : 11;
    const int wsz = (pw == 1) ? 12 : 11;
    ypool[(size_t)b * 576 + e] = pool[c2][ph][pw] / (float)(hsz * wsz);
  }
}

// ---------------------------------------------------------------------------
// K4: out = ypool @ wo + bo
// ---------------------------------------------------------------------------
__global__ __launch_bounds__(256) void k_out(
    const float* __restrict__ ypool, const float* __restrict__ wo,
    const float* __restrict__ bo, float* __restrict__ out) {
  __shared__ float ys[8][576];
  const int t = threadIdx.x;
  const int b0 = blockIdx.x * 8;
  for (int e = t; e < 8 * 576; e += 256) {
    int r = e / 576, i = e % 576;
    ys[r][i] = ypool[(size_t)(b0 + r) * 576 + i];
  }
  __syncthreads();
  for (int j = t; j < 576; j += 256) {
    float acc[8];
    float bb = bo[j];
#pragma unroll
    for (int r = 0; r < 8; r++) acc[r] = bb;
    for (int i = 0; i < 576; i++) {
      float w = wo[(size_t)i * 576 + j];
#pragma unroll
      for (int r = 0; r < 8; r++) acc[r] = fmaf(ys[r][i], w, acc[r]);
    }
#pragma unroll
    for (int r = 0; r < 8; r++) out[(size_t)(b0 + r) * 576 + j] = acc[r];
  }
}

extern "C" void kernel_launch(void* const* d_in, const int* in_sizes, int n_in,
                              void* d_out, int out_size, void* d_ws, size_t ws_size,
                              hipStream_t stream) {
  (void)in_sizes; (void)n_in; (void)out_size; (void)ws_size;
  const float* feat = (const float*)d_in[0];
  const float* cell = (const float*)d_in[1];
  const float* gaze = (const float*)d_in[2];
  const float* w1   = (const float*)d_in[3];
  const float* b1   = (const float*)d_in[4];
  const float* w2   = (const float*)d_in[5];
  const float* b2   = (const float*)d_in[6];
  const float* wv   = (const float*)d_in[7];
  const float* bv   = (const float*)d_in[8];
  const float* ws1  = (const float*)d_in[9];
  const float* bs1  = (const float*)d_in[10];
  const float* ws2  = (const float*)d_in[11];
  const float* bs2  = (const float*)d_in[12];
  const float* ck1  = (const float*)d_in[13];
  const float* cb1  = (const float*)d_in[14];
  const float* ck2  = (const float*)d_in[15];
  const float* cb2  = (const float*)d_in[16];
  const float* wo   = (const float*)d_in[17];
  const float* bo   = (const float*)d_in[18];

  float* out0    = (float*)d_out;                    // (B,576)
  float* updated = out0 + (size_t)NB * 576;          // (B,16,32,32)
  float* wvout   = (float*)d_ws;                     // B*1936 f32
  float* ypool   = wvout + (size_t)NB * NMK;         // B*576 f32
  unsigned short* ap1 = (unsigned short*)(ypool + (size_t)NB * 576);  // 20480 bf16
  unsigned short* ap2 = ap1 + 20480;                                  // 73728 bf16

  k_pack<<<dim3(368), dim3(256), 0, stream>>>(ck1, ck2, ap1, ap2);
  k_mlp<<<dim3(NB / 8), dim3(256), 0, stream>>>(feat, gaze, w1, b1, w2, b2, wv, bv, wvout);
  k_update<<<dim3(NB), dim3(256), 0, stream>>>(cell, gaze, wvout, ws1, bs1, ws2, bs2, updated);
  k_conv3<<<dim3(NB), dim3(256), 0, stream>>>(updated, ap1, cb1, ap2, cb2, ypool);
  k_out<<<dim3(NB / 8), dim3(256), 0, stream>>>(ypool, wo, bo, out0);
}